// Round 5
// baseline (26406.927 us; speedup 1.0000x reference)
//
#include <hip/hip_runtime.h>

// B=64, S=512, H=1024, O=512, L=3
// Multi-launch wavefront-pipelined GRU (no cooperative launch, no grid.sync):
//   cell (t,j) at wavefront w = t+j; per wavefront two kernels, ordered by stream:
//     round1 (304 WGs): z,r,r*h,axg for 3 active cells (64x32 tiles) + fused
//                       out-projection for t3=w-3 from layer-2 h ring
//     round2 (128 WGs): g GEMM + state update -> rings; stage x[:,w+1,:] -> bf16 x-ring
//   ~1032 launches per call, all graph-captured (replay overhead ~2us/node).
// h state kept in BOTH f32 (recurrence math, exact chain) and bf16 (GEMM operand).
// Workspace: 46 MB (bf16 weights 38.8 MB + rings/buffers).

typedef __attribute__((ext_vector_type(8))) short short8;
typedef __attribute__((ext_vector_type(4))) float floatx4;
typedef __attribute__((ext_vector_type(4))) float float4v;
typedef __attribute__((ext_vector_type(4))) short short4v;

#define R1_WGS 304
#define R2_WGS 128
#define NTHR 256

__device__ __forceinline__ unsigned short f2bf(float f) {
  unsigned int u = __float_as_uint(f);
  u += 0x7FFFu + ((u >> 16) & 1u);          // RNE
  return (unsigned short)(u >> 16);
}
__device__ __forceinline__ float bf2f(unsigned short s) {
  return __uint_as_float(((unsigned int)s) << 16);
}
__device__ __forceinline__ float sigmoidf_(float v) {
  return 1.0f / (1.0f + __expf(-v));
}

// acc += A[m0..+31][:1024] @ W[n0..n0+15 rows][:1024]^T ; A,W bf16 (ushort),
// W row-major [n][1024] (K-contiguous). acc0 = rows m0..+15, acc1 = rows m0+16..+31.
// Fragment maps (verified m89/m91): A row = lane&15, k = (lane>>4)*8 + j;
// B col = lane&15, same k map; D row = (lane>>4)*4 + reg, col = lane&15.
__device__ __forceinline__ void kloop(const unsigned short* __restrict__ A, long strideA,
                                      const unsigned short* __restrict__ W,
                                      int m0, int n0, int lane,
                                      floatx4& acc0, floatx4& acc1)
{
  const int l15 = lane & 15, lhi = lane >> 4;
  const short8* ap0 = (const short8*)(A + (long)(m0 + l15) * strideA + lhi * 8);
  const short8* ap1 = (const short8*)(A + (long)(m0 + 16 + l15) * strideA + lhi * 8);
  const short8* wp  = (const short8*)(W + (long)(n0 + l15) * 1024 + lhi * 8);
#pragma unroll 8
  for (int k = 0; k < 32; ++k) {          // K = 32 * 32 = 1024
    short8 bv = wp[k * 4];
    short8 a0 = ap0[k * 4];
    short8 a1 = ap1[k * 4];
    acc0 = __builtin_amdgcn_mfma_f32_16x16x32_bf16(a0, bv, acc0, 0, 0, 0);
    acc1 = __builtin_amdgcn_mfma_f32_16x16x32_bf16(a1, bv, acc1, 0, 0, 0);
  }
}

// ---- phase 0a: cast all weights f32 -> bf16 (19,398,656 elements) ----
__global__ __launch_bounds__(NTHR) void cast_weights(
    const float* __restrict__ Wxz, const float* __restrict__ Wxr,
    const float* __restrict__ Wxg, const float* __restrict__ Whz,
    const float* __restrict__ Whr, const float* __restrict__ Whg,
    const float* __restrict__ Wo, unsigned short* __restrict__ wb)
{
  const float* wsrc[7] = {Wxz, Wxr, Wxg, Whz, Whr, Whg, Wo};
  long base = 0;
  long gtid = (long)blockIdx.x * blockDim.x + threadIdx.x;
  long gsz  = (long)gridDim.x * blockDim.x;
  for (int q = 0; q < 7; ++q) {
    long n4 = (q == 6) ? 131072L : 786432L;       // float4 count
    const float4v* s = (const float4v*)wsrc[q];
    short4v* d = (short4v*)(wb + base);
    for (long i = gtid; i < n4; i += gsz) {
      float4v v = s[i];
      short4v o;
      o[0] = (short)f2bf(v[0]); o[1] = (short)f2bf(v[1]);
      o[2] = (short)f2bf(v[2]); o[3] = (short)f2bf(v[3]);
      d[i] = o;
    }
    base += n4 * 4;
  }
}

// ---- phase 0b: h0 -> ring slot 3 (bf16 + f32), x[:,0,:] -> xring slot 0 ----
__global__ __launch_bounds__(NTHR) void cast_init(
    const float* __restrict__ h0, const float* __restrict__ x,
    unsigned short* __restrict__ ring, float* __restrict__ ringf,
    unsigned short* __restrict__ xring)
{
  long gtid = (long)blockIdx.x * blockDim.x + threadIdx.x;
  long gsz  = (long)gridDim.x * blockDim.x;
  for (long i = gtid; i < 196608L; i += gsz) {   // h0 (b,l,h)
    int b = (int)(i / 3072), rem = (int)(i % 3072);
    int j = rem >> 10, hh = rem & 1023;
    long idx = (long)(j * 4 + 3) * 65536 + b * 1024 + hh;
    float v = h0[i];
    ring[idx]  = f2bf(v);
    ringf[idx] = v;
  }
  for (long i = gtid; i < 65536L; i += gsz)      // x[:,0,:]
    xring[i] = f2bf(x[(long)(i >> 10) * 524288L + (i & 1023)]);
}

// ---- round 1: gates z, r, axg (+ fused out-projection for t3 = w-3) ----
__global__ __launch_bounds__(NTHR) void round1(
    int w, const unsigned short* __restrict__ wb,
    const unsigned short* __restrict__ ring,
    const float* __restrict__ ringf,
    const unsigned short* __restrict__ xring,
    unsigned short* __restrict__ rhb,
    float* __restrict__ zb, float* __restrict__ axgb,
    const float* __restrict__ bhz, const float* __restrict__ bhr,
    const float* __restrict__ bhg, const float* __restrict__ bo,
    float* __restrict__ out)
{
  const int tid  = threadIdx.x;
  const int lane = tid & 63;
  const int l15  = lane & 15, lhi = lane >> 4;
  const int wv   = tid >> 6;
  const int m0t  = (wv & 1) * 32;
  const int n0t  = (wv >> 1) * 16;
  const int wg   = blockIdx.x;

  if (wg < 288) {
    int j = wg / 96, rem = wg % 96, gate = rem / 32, nt = rem % 32;
    int t = w - j;
    if (t < 0 || t >= 512) return;
    const unsigned short* tin =
        (j == 0) ? xring + (long)(t & 3) * 65536
                 : ring + (long)((j - 1) * 4 + (t & 3)) * 65536;
    int n0 = nt * 32 + n0t, colg = n0 + l15;
    floatx4 acc0 = {0.f, 0.f, 0.f, 0.f}, acc1 = {0.f, 0.f, 0.f, 0.f};
    kloop(tin, 1024L, wb + (long)gate * 3145728L + (long)j * 1048576L, m0t, n0, lane, acc0, acc1);
    if (gate == 0) {
      kloop(ring + (long)(j * 4 + ((t - 1) & 3)) * 65536, 1024L,
            wb + 9437184L + (long)j * 1048576L, m0t, n0, lane, acc0, acc1);
      float bz = bhz[j * 1024 + colg];
      float* zbj = zb + j * 65536;
#pragma unroll
      for (int rh = 0; rh < 2; ++rh)
#pragma unroll
        for (int r = 0; r < 4; ++r) {
          int row = m0t + rh * 16 + lhi * 4 + r;
          zbj[row * 1024 + colg] = sigmoidf_((rh ? acc1 : acc0)[r] + bz);
        }
    } else if (gate == 1) {
      kloop(ring + (long)(j * 4 + ((t - 1) & 3)) * 65536, 1024L,
            wb + 12582912L + (long)j * 1048576L, m0t, n0, lane, acc0, acc1);
      float br = bhr[j * 1024 + colg];
      const float* hfj = ringf + (long)(j * 4 + ((t - 1) & 3)) * 65536;
      unsigned short* rhj = rhb + (long)j * 65536;
#pragma unroll
      for (int rh = 0; rh < 2; ++rh)
#pragma unroll
        for (int r = 0; r < 4; ++r) {
          int row = m0t + rh * 16 + lhi * 4 + r;
          float rv = sigmoidf_((rh ? acc1 : acc0)[r] + br);
          rhj[row * 1024 + colg] = f2bf(rv * hfj[row * 1024 + colg]);
        }
    } else {
      float bg = bhg[j * 1024 + colg];
      float* axgj = axgb + j * 65536;
#pragma unroll
      for (int rh = 0; rh < 2; ++rh)
#pragma unroll
        for (int r = 0; r < 4; ++r) {
          int row = m0t + rh * 16 + lhi * 4 + r;
          axgj[row * 1024 + colg] = (rh ? acc1 : acc0)[r] + bg;
        }
    }
  } else {
    int t3 = w - 3;                              // fused out-projection
    if (t3 < 0 || t3 >= 512) return;
    int ot = wg - 288;
    int n0 = ot * 32 + n0t, colg = n0 + l15;
    const unsigned short* A = ring + (long)(2 * 4 + (t3 & 3)) * 65536;
    floatx4 acc0 = {0.f, 0.f, 0.f, 0.f}, acc1 = {0.f, 0.f, 0.f, 0.f};
    kloop(A, 1024L, wb + 18874368L, m0t, n0, lane, acc0, acc1);
    float bov = bo[colg];
#pragma unroll
    for (int rh = 0; rh < 2; ++rh)
#pragma unroll
      for (int r = 0; r < 4; ++r) {
        int b = m0t + rh * 16 + lhi * 4 + r;
        out[((long)b * 512 + t3) * 512 + colg] = (rh ? acc1 : acc0)[r] + bov;
      }
  }
}

// ---- round 2: g GEMM + state update; stage x[:,w+1,:] ----
__global__ __launch_bounds__(NTHR) void round2(
    int w, const unsigned short* __restrict__ wb,
    unsigned short* __restrict__ ring, float* __restrict__ ringf,
    unsigned short* __restrict__ xring,
    const unsigned short* __restrict__ rhb,
    const float* __restrict__ zb, const float* __restrict__ axgb,
    const float* __restrict__ x, float* __restrict__ out)
{
  const int tid  = threadIdx.x;
  const int lane = tid & 63;
  const int l15  = lane & 15, lhi = lane >> 4;
  const int wv   = tid >> 6;
  const int m0t  = (wv & 1) * 32;
  const int n0t  = (wv >> 1) * 16;
  const int wg   = blockIdx.x;

  if (wg < 96) {
    int j = wg / 32, nt = wg % 32, t = w - j;
    if (t < 0 || t >= 512) return;
    int n0 = nt * 32 + n0t, colg = n0 + l15;
    const float* hfj = ringf + (long)(j * 4 + ((t - 1) & 3)) * 65536;
    const float* axgj = axgb + j * 65536;
    const float* zbj  = zb + j * 65536;
    floatx4 acc0, acc1;
#pragma unroll
    for (int r = 0; r < 4; ++r) {
      acc0[r] = axgj[(m0t + lhi * 4 + r) * 1024 + colg];
      acc1[r] = axgj[(m0t + 16 + lhi * 4 + r) * 1024 + colg];
    }
    kloop(rhb + (long)j * 65536, 1024L, wb + 15728640L + (long)j * 1048576L,
          m0t, n0, lane, acc0, acc1);
    unsigned short* ringw = ring + (long)(j * 4 + (t & 3)) * 65536;
    float* ringfw = ringf + (long)(j * 4 + (t & 3)) * 65536;
#pragma unroll
    for (int rh = 0; rh < 2; ++rh)
#pragma unroll
      for (int r = 0; r < 4; ++r) {
        int row = m0t + rh * 16 + lhi * 4 + r;
        float g = tanhf((rh ? acc1 : acc0)[r]);
        float z = zbj[row * 1024 + colg];
        float hp = hfj[row * 1024 + colg];
        float hn = z * hp + (1.f - z) * g;
        ringw[row * 1024 + colg]  = f2bf(hn);
        ringfw[row * 1024 + colg] = hn;
        if (t == 511) out[16777216L + (long)(row * 3 + j) * 1024 + colg] = hn;
      }
  } else if (wg < 112) {
    int tx = w + 1;                              // stage x[:, w+1, :]
    if (tx >= 512) return;
    int swg = wg - 96;
    unsigned short* dst = xring + (long)(tx & 3) * 65536;
#pragma unroll
    for (int u = 0; u < 16; ++u) {
      int i = swg * 4096 + u * 256 + tid;
      dst[i] = f2bf(x[((long)(i >> 10) * 512 + tx) * 1024 + (i & 1023)]);
    }
  }
}

extern "C" void kernel_launch(void* const* d_in, const int* in_sizes, int n_in,
                              void* d_out, int out_size, void* d_ws, size_t ws_size,
                              hipStream_t stream) {
  const float* x   = (const float*)d_in[0];
  const float* h0  = (const float*)d_in[1];
  const float* Wxz = (const float*)d_in[2];
  const float* Wxr = (const float*)d_in[3];
  const float* Wxg = (const float*)d_in[4];
  const float* Whz = (const float*)d_in[5];
  const float* Whr = (const float*)d_in[6];
  const float* Whg = (const float*)d_in[7];
  const float* bhz = (const float*)d_in[8];
  const float* bhr = (const float*)d_in[9];
  const float* bhg = (const float*)d_in[10];
  const float* Wo  = (const float*)d_in[11];
  const float* bo  = (const float*)d_in[12];
  float* out = (float*)d_out;

  // workspace layout (all 16B-aligned)
  unsigned short* wb    = (unsigned short*)d_ws;     // 19,398,656 bf16 weights
  unsigned short* ring  = wb + 19398656L;            // 3*4*65536 bf16 h ring
  unsigned short* xring = ring + 786432L;            // 4*65536 bf16 x ring
  unsigned short* rhb   = xring + 262144L;           // 3*65536 bf16 r*h
  float* zb    = (float*)(rhb + 196608L);            // 3*65536 f32 z
  float* axgb  = zb + 196608L;                       // 3*65536 f32 axg
  float* ringf = axgb + 196608L;                     // 3*4*65536 f32 h ring
  if (ws_size < 46006272UL) return;                  // diagnose via absmax fail

  hipLaunchKernelGGL(cast_weights, dim3(1024), dim3(NTHR), 0, stream,
                     Wxz, Wxr, Wxg, Whz, Whr, Whg, Wo, wb);
  hipLaunchKernelGGL(cast_init, dim3(256), dim3(NTHR), 0, stream,
                     h0, x, ring, ringf, xring);
  for (int w = 0; w < 515; ++w) {
    hipLaunchKernelGGL(round1, dim3(R1_WGS), dim3(NTHR), 0, stream,
                       w, wb, ring, ringf, xring, rhb, zb, axgb, bhz, bhr, bhg, bo, out);
    hipLaunchKernelGGL(round2, dim3(R2_WGS), dim3(NTHR), 0, stream,
                       w, wb, ring, ringf, xring, rhb, zb, axgb, x, out);
  }
}